// Round 6
// baseline (511.110 us; speedup 1.0000x reference)
//
#include <hip/hip_runtime.h>
#include <hip/hip_bf16.h>

// FeatureMixer on MI355X — R6.
// R5 + k1t epilogue fix: par stores were 2B/lane fragment scatter -> L2
// read-for-ownership on every line (FETCH 178MB ~= WRITE 177MB signature).
// Now: acc -> LDS (aliased over As/Bs) -> full-line uint4 streaming stores.

typedef __attribute__((ext_vector_type(8))) __bf16 bf16x8;
typedef __attribute__((ext_vector_type(4))) float f32x4;
typedef __attribute__((ext_vector_type(4))) short short4v;
typedef __attribute__((ext_vector_type(8))) short short8v;

#define BQ_TOT 3600

__device__ __forceinline__ short f2bf(float f) {
  __hip_bfloat16 h = __float2bfloat16(f);
  short s; __builtin_memcpy(&s, &h, 2);
  return s;
}
__device__ __forceinline__ bf16x8 pack8(float4 a, float4 b) {
  short8v o;
  o[0] = f2bf(a.x); o[1] = f2bf(a.y); o[2] = f2bf(a.z); o[3] = f2bf(a.w);
  o[4] = f2bf(b.x); o[5] = f2bf(b.y); o[6] = f2bf(b.z); o[7] = f2bf(b.w);
  return __builtin_bit_cast(bf16x8, o);
}
// exp2-based tanh-approx GELU (max |err| vs exact-erf gelu ~3e-4)
__device__ __forceinline__ float gelu_f(float x) {
  float x2 = x * x;
  float u = x * (0.7978845608f + 0.0356774081f * x2);
  float e = __builtin_amdgcn_exp2f(u * 2.885390082f);  // e^(2u) via v_exp_f32
  float t = 1.0f - 2.0f / (e + 1.0f);                  // tanh(u)
  return 0.5f * x * (1.0f + t);
}
__device__ __forceinline__ void wred2(float& a, float& b) {
#pragma unroll
  for (int m = 32; m >= 1; m >>= 1) {
    a += __shfl_xor(a, m, 64);
    b += __shfl_xor(b, m, 64);
  }
}

// ------------- transpose fp32 [R][C] -> bf16 [C][R] -----------------------
__global__ __launch_bounds__(256) void ktrans_f2b(const float* __restrict__ in,
                                                  short* __restrict__ out,
                                                  int R, int C) {
  __shared__ float t[32][33];
  int tx = threadIdx.x & 31, ty = threadIdx.x >> 5;  // 32 x 8
  int r0 = blockIdx.y * 32, c0 = blockIdx.x * 32;
#pragma unroll
  for (int i = 0; i < 4; i++)
    t[ty + i * 8][tx] = in[(size_t)(r0 + ty + i * 8) * C + c0 + tx];
  __syncthreads();
#pragma unroll
  for (int i = 0; i < 4; i++)
    out[(size_t)(c0 + ty + i * 8) * R + r0 + tx] = f2bf(t[tx][ty + i * 8]);
}

// ------------- K1t: par = X @ W_gen + b_gen, WT pre-transposed bf16 -------
__global__ __launch_bounds__(256) void k1t_gemm(const float* __restrict__ X,
                                                const short* __restrict__ WT,
                                                const float* __restrict__ bg,
                                                short* __restrict__ par,
                                                int nrows) {
  __shared__ short smem[128 * 40 * 2];  // As | Bs ; aliased as Cs in epilogue
  short* As = smem;
  short* Bs = smem + 128 * 40;
  const int tid = threadIdx.x;
  const int rt = blockIdx.x, ct = blockIdx.y;
  const int lane = tid & 63, wv = tid >> 6;
  const int l15 = lane & 15, quad = lane >> 4;
  const int wm = (wv & 1) * 64, wn = (wv >> 1) * 64;
  const int sm = tid >> 1, sk = (tid & 1) * 16;
  f32x4 acc[4][4] = {};
  for (int k0 = 0; k0 < 256; k0 += 32) {
    float4 av[4] = {};
    int gr = rt * 128 + sm;
    if (gr < nrows) {
      const float4* pa = (const float4*)(X + (size_t)gr * 256 + k0 + sk);
      av[0] = pa[0]; av[1] = pa[1]; av[2] = pa[2]; av[3] = pa[3];
    }
    *(short8v*)(void*)(As + sm * 40 + sk) = __builtin_bit_cast(short8v, pack8(av[0], av[1]));
    *(short8v*)(void*)(As + sm * 40 + sk + 8) = __builtin_bit_cast(short8v, pack8(av[2], av[3]));
    const uint4* pb = (const uint4*)(WT + (size_t)(ct * 128 + sm) * 256 + k0 + sk);
    *(uint4*)(Bs + sm * 40 + sk) = pb[0];
    *(uint4*)(Bs + sm * 40 + sk + 8) = pb[1];
    __syncthreads();
    bf16x8 af[4], bfr[4];
#pragma unroll
    for (int i = 0; i < 4; i++)
      af[i] = *(const bf16x8*)(const void*)(As + (wm + i * 16 + l15) * 40 + quad * 8);
#pragma unroll
    for (int j = 0; j < 4; j++)
      bfr[j] = *(const bf16x8*)(const void*)(Bs + (wn + j * 16 + l15) * 40 + quad * 8);
#pragma unroll
    for (int i = 0; i < 4; i++)
#pragma unroll
      for (int j = 0; j < 4; j++)
        acc[i][j] = __builtin_amdgcn_mfma_f32_16x16x32_bf16(af[i], bfr[j], acc[i][j], 0, 0, 0);
    __syncthreads();
  }
  // -------- epilogue: restage through LDS, full-line streaming stores -----
  short* Cs = smem;  // 64 x 136 shorts = 17408 B <= 20480 B
#pragma unroll
  for (int h = 0; h < 2; h++) {
    if ((wv & 1) == h) {
#pragma unroll
      for (int i = 0; i < 4; i++)
#pragma unroll
        for (int j = 0; j < 4; j++) {
          float bgv = bg[ct * 128 + wn + j * 16 + l15];
#pragma unroll
          for (int r = 0; r < 4; r++)
            Cs[(i * 16 + quad * 4 + r) * 136 + wn + j * 16 + l15] =
                f2bf(acc[i][j][r] + bgv);
        }
    }
    __syncthreads();
#pragma unroll
    for (int it = 0; it < 4; it++) {
      int rr = it * 16 + (tid >> 4);
      int cc = (tid & 15) * 8;
      uint4 v = *(const uint4*)(const void*)(Cs + rr * 136 + cc);
      int row = rt * 128 + h * 64 + rr;
      if (row < nrows)
        *(uint4*)(par + (size_t)row * 24576 + ct * 128 + cc) = v;
    }
    __syncthreads();
  }
}

// ------------- K1: fallback (in-kernel W_gen transpose, fp32) -------------
__global__ __launch_bounds__(256) void k1_gemm(const float* __restrict__ X,
                                               const float* __restrict__ Wg,
                                               const float* __restrict__ bg,
                                               short* __restrict__ par,
                                               int nrows) {
  __shared__ short As[128 * 40];
  __shared__ short Bs[128 * 40];
  const int tid = threadIdx.x;
  const int rt = blockIdx.x, ct = blockIdx.y;
  const int lane = tid & 63, wv = tid >> 6;
  const int l15 = lane & 15, quad = lane >> 4;
  const int wm = (wv & 1) * 64, wn = (wv >> 1) * 64;
  const int sm = tid >> 1, sk = (tid & 1) * 16;
  const int bk = tid >> 3, bn0 = (tid & 7) * 16;
  f32x4 acc[4][4] = {};
  for (int k0 = 0; k0 < 256; k0 += 32) {
    float4 av[4] = {};
    int gr = rt * 128 + sm;
    if (gr < nrows) {
      const float4* pa = (const float4*)(X + (size_t)gr * 256 + k0 + sk);
      av[0] = pa[0]; av[1] = pa[1]; av[2] = pa[2]; av[3] = pa[3];
    }
    *(short8v*)(void*)(As + sm * 40 + sk) = __builtin_bit_cast(short8v, pack8(av[0], av[1]));
    *(short8v*)(void*)(As + sm * 40 + sk + 8) = __builtin_bit_cast(short8v, pack8(av[2], av[3]));
    const float4* pb = (const float4*)(Wg + (size_t)(k0 + bk) * 24576 + ct * 128 + bn0);
    float4 b0 = pb[0], b1 = pb[1], b2 = pb[2], b3 = pb[3];
    short* bd = Bs + bn0 * 40 + bk;
    bd[0 * 40] = f2bf(b0.x); bd[1 * 40] = f2bf(b0.y); bd[2 * 40] = f2bf(b0.z); bd[3 * 40] = f2bf(b0.w);
    bd[4 * 40] = f2bf(b1.x); bd[5 * 40] = f2bf(b1.y); bd[6 * 40] = f2bf(b1.z); bd[7 * 40] = f2bf(b1.w);
    bd[8 * 40] = f2bf(b2.x); bd[9 * 40] = f2bf(b2.y); bd[10 * 40] = f2bf(b2.z); bd[11 * 40] = f2bf(b2.w);
    bd[12 * 40] = f2bf(b3.x); bd[13 * 40] = f2bf(b3.y); bd[14 * 40] = f2bf(b3.z); bd[15 * 40] = f2bf(b3.w);
    __syncthreads();
    bf16x8 af[4], bfr[4];
#pragma unroll
    for (int i = 0; i < 4; i++)
      af[i] = *(const bf16x8*)(const void*)(As + (wm + i * 16 + l15) * 40 + quad * 8);
#pragma unroll
    for (int j = 0; j < 4; j++)
      bfr[j] = *(const bf16x8*)(const void*)(Bs + (wn + j * 16 + l15) * 40 + quad * 8);
#pragma unroll
    for (int i = 0; i < 4; i++)
#pragma unroll
      for (int j = 0; j < 4; j++)
        acc[i][j] = __builtin_amdgcn_mfma_f32_16x16x32_bf16(af[i], bfr[j], acc[i][j], 0, 0, 0);
    __syncthreads();
  }
#pragma unroll
  for (int i = 0; i < 4; i++) {
#pragma unroll
    for (int j = 0; j < 4; j++) {
      int col = ct * 128 + wn + j * 16 + l15;
      float bgv = bg[col];
#pragma unroll
      for (int r = 0; r < 4; r++) {
        int row = rt * 128 + wm + i * 16 + quad * 4 + r;
        if (row < nrows)
          par[(size_t)row * 24576 + col] = f2bf(acc[i][j][r] + bgv);
      }
    }
  }
}

// ------------- K2w: one wave per (bq, head) -------------------------------
__global__ __launch_bounds__(64, 3) void k2_mixw(const float* __restrict__ sf,
                                                 const short* __restrict__ par,
                                                 short* __restrict__ U) {
  __shared__ short p1T[64 * 68];  // [d][c], stride 68
  __shared__ short Tl[64 * 40];   // [d][p] stride 40; reused as U-stage [32][72]
  const int bq = blockIdx.x >> 2, hd = blockIdx.x & 3;
  const int lane = threadIdx.x & 63;
  const int l15 = lane & 15, quad = lane >> 4;
  const short* pp1 = par + (size_t)bq * 24576 + hd * 4096;
#pragma unroll
  for (int it = 0; it < 8; it++) {
    int c = it * 8 + (lane >> 3);
    int d0 = (lane & 7) * 8;
    short8v tv = *(const short8v*)(const void*)(pp1 + c * 64 + d0);
#pragma unroll
    for (int i = 0; i < 8; i++) p1T[(d0 + i) * 68 + c] = tv[i];
  }
  __syncthreads();
  const float* psf = sf + (size_t)bq * 8192 + hd * 2048;
  bf16x8 sa[2][2];
#pragma unroll
  for (int tm = 0; tm < 2; tm++)
#pragma unroll
    for (int kk = 0; kk < 2; kk++) {
      const float* p = psf + (tm * 16 + l15) * 64 + kk * 32 + quad * 8;
      sa[tm][kk] = pack8(*(const float4*)p, *(const float4*)(p + 4));
    }
  f32x4 acc1[2][4] = {};
#pragma unroll
  for (int kk = 0; kk < 2; kk++) {
#pragma unroll
    for (int tn = 0; tn < 4; tn++) {
      const short* bp = p1T + (tn * 16 + l15) * 68 + kk * 32 + quad * 8;
      short4v lo = *(const short4v*)(const void*)bp;
      short4v hi = *(const short4v*)(const void*)(bp + 4);
      bf16x8 bfr = __builtin_bit_cast(bf16x8, __builtin_shufflevector(lo, hi, 0, 1, 2, 3, 4, 5, 6, 7));
#pragma unroll
      for (int tm = 0; tm < 2; tm++)
        acc1[tm][tn] = __builtin_amdgcn_mfma_f32_16x16x32_bf16(sa[tm][kk], bfr, acc1[tm][tn], 0, 0, 0);
    }
  }
  float s1 = 0.f, s2 = 0.f;
#pragma unroll
  for (int tm = 0; tm < 2; tm++)
#pragma unroll
    for (int tn = 0; tn < 4; tn++)
#pragma unroll
      for (int r = 0; r < 4; r++) {
        float g = gelu_f(acc1[tm][tn][r]);
        acc1[tm][tn][r] = g;
        s1 += g; s2 += g * g;
      }
  wred2(s1, s2);
  float mean = s1 * (1.f / 2048.f);
  float rstd = rsqrtf(fmaxf(s2 * (1.f / 2048.f) - mean * mean, 0.f) + 1e-5f);
#pragma unroll
  for (int tm = 0; tm < 2; tm++)
#pragma unroll
    for (int tn = 0; tn < 4; tn++) {
      short4v o;
#pragma unroll
      for (int r = 0; r < 4; r++) o[r] = f2bf((acc1[tm][tn][r] - mean) * rstd);
      *(short4v*)(void*)(Tl + (tn * 16 + l15) * 40 + tm * 16 + quad * 4) = o;
    }
  __syncthreads();
  const short* pp2 = par + (size_t)bq * 24576 + 16384 + hd * 2048;
  bf16x8 a2[4], b2[4];
#pragma unroll
  for (int t = 0; t < 4; t++) {
    a2[t] = *(const bf16x8*)(const void*)(pp2 + (t * 16 + l15) * 32 + quad * 8);
    b2[t] = *(const bf16x8*)(const void*)(Tl + (t * 16 + l15) * 40 + quad * 8);
  }
  f32x4 acc2[4][4] = {};
#pragma unroll
  for (int tm = 0; tm < 4; tm++)
#pragma unroll
    for (int tn = 0; tn < 4; tn++)
      acc2[tm][tn] = __builtin_amdgcn_mfma_f32_16x16x32_bf16(a2[tm], b2[tn], acc2[tm][tn], 0, 0, 0);
  float u1 = 0.f, u2 = 0.f;
#pragma unroll
  for (int tm = 0; tm < 4; tm++)
#pragma unroll
    for (int tn = 0; tn < 4; tn++)
#pragma unroll
      for (int r = 0; r < 4; r++) {
        float g = gelu_f(acc2[tm][tn][r]);
        acc2[tm][tn][r] = g;
        u1 += g; u2 += g * g;
      }
  wred2(u1, u2);
  float m2 = u1 * (1.f / 4096.f);
  float rs2 = rsqrtf(fmaxf(u2 * (1.f / 4096.f) - m2 * m2, 0.f) + 1e-5f);
  short* pu = U + (size_t)bq * 16384 + hd * 4096;  // [e][d]
#pragma unroll
  for (int h2 = 0; h2 < 2; h2++) {
    __syncthreads();
#pragma unroll
    for (int tmh = 0; tmh < 2; tmh++) {
      int tm = h2 * 2 + tmh;
#pragma unroll
      for (int tn = 0; tn < 4; tn++)
#pragma unroll
        for (int r = 0; r < 4; r++) {
          int er = tmh * 16 + quad * 4 + r;
          Tl[er * 72 + tn * 16 + l15] = f2bf((acc2[tm][tn][r] - m2) * rs2);
        }
    }
    __syncthreads();
#pragma unroll
    for (int i = 0; i < 4; i++) {
      int er = i * 8 + (lane >> 3);
      int dch = (lane & 7) * 8;
      uint4 v = *(const uint4*)(const void*)(Tl + er * 72 + dch);
      *(uint4*)(void*)(pu + (size_t)(h2 * 32 + er) * 64 + dch) = v;
    }
  }
}

// ------------- K3t: split-K(4) C2p[seg] = U @ W_out, WT pre-transposed ----
__global__ __launch_bounds__(256) void k3t_gemm(const short* __restrict__ U,
                                                const short* __restrict__ WT,
                                                float* __restrict__ C2p,
                                                int nrows) {
  __shared__ short As[64 * 72];
  __shared__ short Bs[64 * 72];
  const int tid = threadIdx.x;
  const int bm = blockIdx.x, bn = blockIdx.y, seg = blockIdx.z;
  const int lane = tid & 63, wv = tid >> 6;
  const int l15 = lane & 15, quad = lane >> 4;
  const int wm = (wv & 1) * 32, wn = (wv >> 1) * 32;
  const int sr = tid >> 2, sk = (tid & 3) * 16;
  f32x4 acc[2][2] = {};
  int k0 = seg * 4096;
  for (int kt = 0; kt < 64; kt++, k0 += 64) {
    uint4 a0 = {0, 0, 0, 0}, a1 = {0, 0, 0, 0};
    int gr = bm * 64 + sr;
    if (gr < nrows) {
      const uint4* pa = (const uint4*)(U + (size_t)gr * 16384 + k0 + sk);
      a0 = pa[0]; a1 = pa[1];
    }
    *(uint4*)(As + sr * 72 + sk) = a0;
    *(uint4*)(As + sr * 72 + sk + 8) = a1;
    const uint4* pb = (const uint4*)(WT + (size_t)(bn * 64 + sr) * 16384 + k0 + sk);
    *(uint4*)(Bs + sr * 72 + sk) = pb[0];
    *(uint4*)(Bs + sr * 72 + sk + 8) = pb[1];
    __syncthreads();
#pragma unroll
    for (int kk = 0; kk < 64; kk += 32) {
      bf16x8 af[2], bfr[2];
#pragma unroll
      for (int i = 0; i < 2; i++)
        af[i] = *(const bf16x8*)(const void*)(As + (wm + i * 16 + l15) * 72 + kk + quad * 8);
#pragma unroll
      for (int j = 0; j < 2; j++)
        bfr[j] = *(const bf16x8*)(const void*)(Bs + (wn + j * 16 + l15) * 72 + kk + quad * 8);
#pragma unroll
      for (int i = 0; i < 2; i++)
#pragma unroll
        for (int j = 0; j < 2; j++)
          acc[i][j] = __builtin_amdgcn_mfma_f32_16x16x32_bf16(af[i], bfr[j], acc[i][j], 0, 0, 0);
    }
    __syncthreads();
  }
#pragma unroll
  for (int i = 0; i < 2; i++)
#pragma unroll
    for (int j = 0; j < 2; j++)
#pragma unroll
      for (int r = 0; r < 4; r++) {
        int row = bm * 64 + wm + i * 16 + quad * 4 + r;
        if (row < nrows)
          C2p[((size_t)seg * nrows + row) * 256 + bn * 64 + wn + j * 16 + l15] = acc[i][j][r];
      }
}

// ------------- K3: fallback (in-kernel W_out transpose, fp32) -------------
__global__ __launch_bounds__(256) void k3_gemm(const short* __restrict__ U,
                                               const float* __restrict__ Wo,
                                               float* __restrict__ C2p,
                                               int nrows) {
  __shared__ short As[64 * 72];
  __shared__ short Bs[64 * 72];
  const int tid = threadIdx.x;
  const int bm = blockIdx.x, bn = blockIdx.y, seg = blockIdx.z;
  const int lane = tid & 63, wv = tid >> 6;
  const int l15 = lane & 15, quad = lane >> 4;
  const int wm = (wv & 1) * 32, wn = (wv >> 1) * 32;
  const int sr = tid >> 2, sk = (tid & 3) * 16;
  const int bk = tid >> 2, bn0 = (tid & 3) * 16;
  f32x4 acc[2][2] = {};
  int k0 = seg * 4096;
  for (int kt = 0; kt < 64; kt++, k0 += 64) {
    uint4 a0 = {0, 0, 0, 0}, a1 = {0, 0, 0, 0};
    int gr = bm * 64 + sr;
    if (gr < nrows) {
      const uint4* pa = (const uint4*)(U + (size_t)gr * 16384 + k0 + sk);
      a0 = pa[0]; a1 = pa[1];
    }
    *(uint4*)(As + sr * 72 + sk) = a0;
    *(uint4*)(As + sr * 72 + sk + 8) = a1;
    const float4* pb = (const float4*)(Wo + (size_t)(k0 + bk) * 256 + bn * 64 + bn0);
    float4 b0 = pb[0], b1 = pb[1], b2 = pb[2], b3 = pb[3];
    short* bd = Bs + bn0 * 72 + bk;
    bd[0 * 72] = f2bf(b0.x); bd[1 * 72] = f2bf(b0.y); bd[2 * 72] = f2bf(b0.z); bd[3 * 72] = f2bf(b0.w);
    bd[4 * 72] = f2bf(b1.x); bd[5 * 72] = f2bf(b1.y); bd[6 * 72] = f2bf(b1.z); bd[7 * 72] = f2bf(b1.w);
    bd[8 * 72] = f2bf(b2.x); bd[9 * 72] = f2bf(b2.y); bd[10 * 72] = f2bf(b2.z); bd[11 * 72] = f2bf(b2.w);
    bd[12 * 72] = f2bf(b3.x); bd[13 * 72] = f2bf(b3.y); bd[14 * 72] = f2bf(b3.z); bd[15 * 72] = f2bf(b3.w);
    __syncthreads();
#pragma unroll
    for (int kk = 0; kk < 64; kk += 32) {
      bf16x8 af[2], bfr[2];
#pragma unroll
      for (int i = 0; i < 2; i++)
        af[i] = *(const bf16x8*)(const void*)(As + (wm + i * 16 + l15) * 72 + kk + quad * 8);
#pragma unroll
      for (int j = 0; j < 2; j++)
        bfr[j] = *(const bf16x8*)(const void*)(Bs + (wn + j * 16 + l15) * 72 + kk + quad * 8);
#pragma unroll
      for (int i = 0; i < 2; i++)
#pragma unroll
        for (int j = 0; j < 2; j++)
          acc[i][j] = __builtin_amdgcn_mfma_f32_16x16x32_bf16(af[i], bfr[j], acc[i][j], 0, 0, 0);
    }
    __syncthreads();
  }
#pragma unroll
  for (int i = 0; i < 2; i++)
#pragma unroll
    for (int j = 0; j < 2; j++)
#pragma unroll
      for (int r = 0; r < 4; r++) {
        int row = bm * 64 + wm + i * 16 + quad * 4 + r;
        if (row < nrows)
          C2p[((size_t)seg * nrows + row) * 256 + bn * 64 + wn + j * 16 + l15] = acc[i][j][r];
      }
}

// ------------- K4: reduce 4 partials + b_out + affine LayerNorm -----------
__global__ __launch_bounds__(256) void k4_ln(const float* __restrict__ C2p,
                                             const float* __restrict__ bo,
                                             const float* __restrict__ lnw,
                                             const float* __restrict__ lnb,
                                             float* __restrict__ out,
                                             int nrows) {
  int row = blockIdx.x * 4 + (threadIdx.x >> 6);
  if (row >= nrows) return;
  int lane = threadIdx.x & 63;
  float v[4] = {0.f, 0.f, 0.f, 0.f};
#pragma unroll
  for (int s = 0; s < 4; s++) {
    const float4* p = (const float4*)(C2p + ((size_t)s * nrows + row) * 256) + lane;
    float4 t = *p;
    v[0] += t.x; v[1] += t.y; v[2] += t.z; v[3] += t.w;
  }
  float4 bov = *((const float4*)bo + lane);
  v[0] += bov.x; v[1] += bov.y; v[2] += bov.z; v[3] += bov.w;
  float s1 = v[0] + v[1] + v[2] + v[3];
  float s2 = v[0] * v[0] + v[1] * v[1] + v[2] * v[2] + v[3] * v[3];
  wred2(s1, s2);
  float mean = s1 * (1.f / 256.f);
  float rstd = rsqrtf(fmaxf(s2 * (1.f / 256.f) - mean * mean, 0.f) + 1e-5f);
  float4 wv = *((const float4*)lnw + lane);
  float4 bv = *((const float4*)lnb + lane);
  float4 o;
  o.x = (v[0] - mean) * rstd * wv.x + bv.x;
  o.y = (v[1] - mean) * rstd * wv.y + bv.y;
  o.z = (v[2] - mean) * rstd * wv.z + bv.z;
  o.w = (v[3] - mean) * rstd * wv.w + bv.w;
  *((float4*)(out + (size_t)row * 256) + lane) = o;
}

extern "C" void kernel_launch(void* const* d_in, const int* in_sizes, int n_in,
                              void* d_out, int out_size, void* d_ws, size_t ws_size,
                              hipStream_t stream) {
  const float* qf  = (const float*)d_in[0];
  const float* sf  = (const float*)d_in[1];
  const float* Wg  = (const float*)d_in[2];
  const float* bg  = (const float*)d_in[3];
  const float* Wo  = (const float*)d_in[4];
  const float* bo  = (const float*)d_in[5];
  const float* lnw = (const float*)d_in[6];
  const float* lnb = (const float*)d_in[7];
  char* wsb = (char*)d_ws;

  const size_t sz_par = (size_t)BQ_TOT * 24576 * 2;   // 176.9 MB
  const size_t sz_U   = (size_t)BQ_TOT * 16384 * 2;   // 118.0 MB
  const size_t sz_C2  = (size_t)4 * BQ_TOT * 256 * 4; //  14.7 MB
  const size_t sz_WTg = (size_t)24576 * 256 * 2;      //  12.6 MB
  const size_t sz_WTo = (size_t)16384 * 256 * 2;      //   8.4 MB
  const size_t NEED   = sz_WTg + sz_WTo + sz_par + sz_U + sz_C2;  // 330.6 MB

  if (ws_size >= NEED) {
    short* WTg = (short*)wsb;
    short* WTo = (short*)(wsb + sz_WTg);
    short* par = (short*)(wsb + sz_WTg + sz_WTo);
    short* Uc  = (short*)(wsb + sz_WTg + sz_WTo + sz_par);
    float* C2p = (float*)(wsb + sz_WTg + sz_WTo + sz_par + sz_U);
    ktrans_f2b<<<dim3(768, 8), 256, 0, stream>>>(Wg, WTg, 256, 24576);
    ktrans_f2b<<<dim3(8, 512), 256, 0, stream>>>(Wo, WTo, 16384, 256);
    k1t_gemm<<<dim3(29, 192), 256, 0, stream>>>(qf, WTg, bg, par, BQ_TOT);
    k2_mixw<<<dim3(BQ_TOT * 4), 64, 0, stream>>>(sf, par, Uc);
    k3t_gemm<<<dim3(57, 4, 4), 256, 0, stream>>>(Uc, WTo, C2p, BQ_TOT);
    k4_ln<<<dim3(900), 256, 0, stream>>>(C2p, bo, lnw, lnb, (float*)d_out, BQ_TOT);
  } else {
    // chunked fallback: per-row 24576*2 + 16384*2 + 4*256*4 = 86016 B
    const size_t per_row = 86016;
    long long chunk_ll = (long long)(ws_size / per_row);
    int chunk = (chunk_ll > BQ_TOT) ? BQ_TOT : (int)chunk_ll;
    if (chunk < 8) chunk = 8;
    short* par = (short*)wsb;
    short* Uc  = (short*)(wsb + (size_t)chunk * 24576 * 2);
    float* C2p = (float*)(wsb + (size_t)chunk * 24576 * 2 + (size_t)chunk * 16384 * 2);
    for (int rb = 0; rb < BQ_TOT; rb += chunk) {
      int r = (BQ_TOT - rb < chunk) ? (BQ_TOT - rb) : chunk;
      k1_gemm<<<dim3((r + 127) / 128, 192), 256, 0, stream>>>(
          qf + (size_t)rb * 256, Wg, bg, par, r);
      k2_mixw<<<dim3(r * 4), 64, 0, stream>>>(sf + (size_t)rb * 8192, par, Uc);
      k3_gemm<<<dim3((r + 63) / 64, 4, 4), 256, 0, stream>>>(Uc, Wo, C2p, r);
      k4_ln<<<dim3((r + 3) / 4), 256, 0, stream>>>(
          C2p, bo, lnw, lnb, (float*)d_out + (size_t)rb * 256, r);
    }
  }
}

// Round 7
// 455.532 us; speedup vs baseline: 1.1220x; 1.1220x over previous
//
#include <hip/hip_runtime.h>
#include <hip/hip_bf16.h>

// FeatureMixer on MI355X — R7.
// R6 post-mortem: k1t is L2-miss-path bound (391 MB @ ~2.5 TB/s; dur invariant
// to occupancy). Fixes: (1) k1t XCD-partitioned ct swizzle (xcd=b&7 owns 24
// WT tiles -> L2-resident) + X pre-converted to bf16; (2) k3x: full-N=256 per
// block, U read ONCE, split-K(16) XCD-partitioned; (3) C2p aliases par.

typedef __attribute__((ext_vector_type(8))) __bf16 bf16x8;
typedef __attribute__((ext_vector_type(4))) float f32x4;
typedef __attribute__((ext_vector_type(4))) short short4v;
typedef __attribute__((ext_vector_type(8))) short short8v;

#define BQ_TOT 3600

__device__ __forceinline__ short f2bf(float f) {
  __hip_bfloat16 h = __float2bfloat16(f);
  short s; __builtin_memcpy(&s, &h, 2);
  return s;
}
__device__ __forceinline__ bf16x8 pack8(float4 a, float4 b) {
  short8v o;
  o[0] = f2bf(a.x); o[1] = f2bf(a.y); o[2] = f2bf(a.z); o[3] = f2bf(a.w);
  o[4] = f2bf(b.x); o[5] = f2bf(b.y); o[6] = f2bf(b.z); o[7] = f2bf(b.w);
  return __builtin_bit_cast(bf16x8, o);
}
// exp2-based tanh-approx GELU (max |err| vs exact-erf gelu ~3e-4)
__device__ __forceinline__ float gelu_f(float x) {
  float x2 = x * x;
  float u = x * (0.7978845608f + 0.0356774081f * x2);
  float e = __builtin_amdgcn_exp2f(u * 2.885390082f);
  float t = 1.0f - 2.0f / (e + 1.0f);
  return 0.5f * x * (1.0f + t);
}
__device__ __forceinline__ void wred2(float& a, float& b) {
#pragma unroll
  for (int m = 32; m >= 1; m >>= 1) {
    a += __shfl_xor(a, m, 64);
    b += __shfl_xor(b, m, 64);
  }
}

// ------------- kcvt: fp32 -> bf16 flat (N multiple of 2048) ---------------
__global__ __launch_bounds__(256) void kcvt_f2b(const float* __restrict__ in,
                                                short* __restrict__ out) {
  int idx = (blockIdx.x * 256 + threadIdx.x) * 8;
  const float4* p = (const float4*)(in + idx);
  *(short8v*)(void*)(out + idx) = __builtin_bit_cast(short8v, pack8(p[0], p[1]));
}

// ------------- transpose fp32 [R][C] -> bf16 [C][R] -----------------------
__global__ __launch_bounds__(256) void ktrans_f2b(const float* __restrict__ in,
                                                  short* __restrict__ out,
                                                  int R, int C) {
  __shared__ float t[32][33];
  int tx = threadIdx.x & 31, ty = threadIdx.x >> 5;  // 32 x 8
  int r0 = blockIdx.y * 32, c0 = blockIdx.x * 32;
#pragma unroll
  for (int i = 0; i < 4; i++)
    t[ty + i * 8][tx] = in[(size_t)(r0 + ty + i * 8) * C + c0 + tx];
  __syncthreads();
#pragma unroll
  for (int i = 0; i < 4; i++)
    out[(size_t)(c0 + ty + i * 8) * R + r0 + tx] = f2bf(t[tx][ty + i * 8]);
}

// ------------- K1t: par = Xb @ W_gen + b_gen; XCD-local ct ----------------
// Xb: [nrows][256] bf16, WT: [24576][256] bf16, par: [nrows][24576] bf16
// grid 5568 = 8 xcd * 24 ct' * 29 rt; xcd = b&7 owns ct range [xcd*24, +24)
__global__ __launch_bounds__(256) void k1t_gemm(const short* __restrict__ Xb,
                                                const short* __restrict__ WT,
                                                const float* __restrict__ bg,
                                                short* __restrict__ par,
                                                int nrows) {
  __shared__ short smem[128 * 40 * 2];  // As | Bs ; aliased as Cs in epilogue
  short* As = smem;
  short* Bs = smem + 128 * 40;
  const int b = blockIdx.x;
  const int xcd = b & 7, i = b >> 3;
  const int ct = xcd * 24 + i / 29;
  const int rt = i % 29;
  const int tid = threadIdx.x;
  const int lane = tid & 63, wv = tid >> 6;
  const int l15 = lane & 15, quad = lane >> 4;
  const int wm = (wv & 1) * 64, wn = (wv >> 1) * 64;
  const int sm = tid >> 1, sk = (tid & 1) * 16;
  f32x4 acc[4][4] = {};
  for (int k0 = 0; k0 < 256; k0 += 32) {
    uint4 a0 = {0, 0, 0, 0}, a1 = {0, 0, 0, 0};
    int gr = rt * 128 + sm;
    if (gr < nrows) {
      const uint4* pa = (const uint4*)(Xb + (size_t)gr * 256 + k0 + sk);
      a0 = pa[0]; a1 = pa[1];
    }
    *(uint4*)(As + sm * 40 + sk) = a0;
    *(uint4*)(As + sm * 40 + sk + 8) = a1;
    const uint4* pb = (const uint4*)(WT + (size_t)(ct * 128 + sm) * 256 + k0 + sk);
    *(uint4*)(Bs + sm * 40 + sk) = pb[0];
    *(uint4*)(Bs + sm * 40 + sk + 8) = pb[1];
    __syncthreads();
    bf16x8 af[4], bfr[4];
#pragma unroll
    for (int i2 = 0; i2 < 4; i2++)
      af[i2] = *(const bf16x8*)(const void*)(As + (wm + i2 * 16 + l15) * 40 + quad * 8);
#pragma unroll
    for (int j = 0; j < 4; j++)
      bfr[j] = *(const bf16x8*)(const void*)(Bs + (wn + j * 16 + l15) * 40 + quad * 8);
#pragma unroll
    for (int i2 = 0; i2 < 4; i2++)
#pragma unroll
      for (int j = 0; j < 4; j++)
        acc[i2][j] = __builtin_amdgcn_mfma_f32_16x16x32_bf16(af[i2], bfr[j], acc[i2][j], 0, 0, 0);
    __syncthreads();
  }
  // epilogue: restage through LDS, full-line streaming stores
  short* Cs = smem;  // 64 x 136 shorts
#pragma unroll
  for (int h = 0; h < 2; h++) {
    if ((wv & 1) == h) {
#pragma unroll
      for (int i2 = 0; i2 < 4; i2++)
#pragma unroll
        for (int j = 0; j < 4; j++) {
          float bgv = bg[ct * 128 + wn + j * 16 + l15];
#pragma unroll
          for (int r = 0; r < 4; r++)
            Cs[(i2 * 16 + quad * 4 + r) * 136 + wn + j * 16 + l15] =
                f2bf(acc[i2][j][r] + bgv);
        }
    }
    __syncthreads();
#pragma unroll
    for (int it = 0; it < 4; it++) {
      int rr = it * 16 + (tid >> 4);
      int cc = (tid & 15) * 8;
      uint4 v = *(const uint4*)(const void*)(Cs + rr * 136 + cc);
      int row = rt * 128 + h * 64 + rr;
      if (row < nrows)
        *(uint4*)(par + (size_t)row * 24576 + ct * 128 + cc) = v;
    }
    __syncthreads();
  }
}

// ------------- K1: fallback (in-kernel W_gen transpose, fp32 X) -----------
__global__ __launch_bounds__(256) void k1_gemm(const float* __restrict__ X,
                                               const float* __restrict__ Wg,
                                               const float* __restrict__ bg,
                                               short* __restrict__ par,
                                               int nrows) {
  __shared__ short As[128 * 40];
  __shared__ short Bs[128 * 40];
  const int tid = threadIdx.x;
  const int rt = blockIdx.x, ct = blockIdx.y;
  const int lane = tid & 63, wv = tid >> 6;
  const int l15 = lane & 15, quad = lane >> 4;
  const int wm = (wv & 1) * 64, wn = (wv >> 1) * 64;
  const int sm = tid >> 1, sk = (tid & 1) * 16;
  const int bk = tid >> 3, bn0 = (tid & 7) * 16;
  f32x4 acc[4][4] = {};
  for (int k0 = 0; k0 < 256; k0 += 32) {
    float4 av[4] = {};
    int gr = rt * 128 + sm;
    if (gr < nrows) {
      const float4* pa = (const float4*)(X + (size_t)gr * 256 + k0 + sk);
      av[0] = pa[0]; av[1] = pa[1]; av[2] = pa[2]; av[3] = pa[3];
    }
    *(short8v*)(void*)(As + sm * 40 + sk) = __builtin_bit_cast(short8v, pack8(av[0], av[1]));
    *(short8v*)(void*)(As + sm * 40 + sk + 8) = __builtin_bit_cast(short8v, pack8(av[2], av[3]));
    const float4* pb = (const float4*)(Wg + (size_t)(k0 + bk) * 24576 + ct * 128 + bn0);
    float4 b0 = pb[0], b1 = pb[1], b2 = pb[2], b3 = pb[3];
    short* bd = Bs + bn0 * 40 + bk;
    bd[0 * 40] = f2bf(b0.x); bd[1 * 40] = f2bf(b0.y); bd[2 * 40] = f2bf(b0.z); bd[3 * 40] = f2bf(b0.w);
    bd[4 * 40] = f2bf(b1.x); bd[5 * 40] = f2bf(b1.y); bd[6 * 40] = f2bf(b1.z); bd[7 * 40] = f2bf(b1.w);
    bd[8 * 40] = f2bf(b2.x); bd[9 * 40] = f2bf(b2.y); bd[10 * 40] = f2bf(b2.z); bd[11 * 40] = f2bf(b2.w);
    bd[12 * 40] = f2bf(b3.x); bd[13 * 40] = f2bf(b3.y); bd[14 * 40] = f2bf(b3.z); bd[15 * 40] = f2bf(b3.w);
    __syncthreads();
    bf16x8 af[4], bfr[4];
#pragma unroll
    for (int i = 0; i < 4; i++)
      af[i] = *(const bf16x8*)(const void*)(As + (wm + i * 16 + l15) * 40 + quad * 8);
#pragma unroll
    for (int j = 0; j < 4; j++)
      bfr[j] = *(const bf16x8*)(const void*)(Bs + (wn + j * 16 + l15) * 40 + quad * 8);
#pragma unroll
    for (int i = 0; i < 4; i++)
#pragma unroll
      for (int j = 0; j < 4; j++)
        acc[i][j] = __builtin_amdgcn_mfma_f32_16x16x32_bf16(af[i], bfr[j], acc[i][j], 0, 0, 0);
    __syncthreads();
  }
#pragma unroll
  for (int i = 0; i < 4; i++) {
#pragma unroll
    for (int j = 0; j < 4; j++) {
      int col = ct * 128 + wn + j * 16 + l15;
      float bgv = bg[col];
#pragma unroll
      for (int r = 0; r < 4; r++) {
        int row = rt * 128 + wm + i * 16 + quad * 4 + r;
        if (row < nrows)
          par[(size_t)row * 24576 + col] = f2bf(acc[i][j][r] + bgv);
      }
    }
  }
}

// ------------- K2w: one wave per (bq, head) -------------------------------
__global__ __launch_bounds__(64, 3) void k2_mixw(const float* __restrict__ sf,
                                                 const short* __restrict__ par,
                                                 short* __restrict__ U) {
  __shared__ short p1T[64 * 68];
  __shared__ short Tl[64 * 40];   // reused as U-stage [32][72]
  const int bq = blockIdx.x >> 2, hd = blockIdx.x & 3;
  const int lane = threadIdx.x & 63;
  const int l15 = lane & 15, quad = lane >> 4;
  const short* pp1 = par + (size_t)bq * 24576 + hd * 4096;
#pragma unroll
  for (int it = 0; it < 8; it++) {
    int c = it * 8 + (lane >> 3);
    int d0 = (lane & 7) * 8;
    short8v tv = *(const short8v*)(const void*)(pp1 + c * 64 + d0);
#pragma unroll
    for (int i = 0; i < 8; i++) p1T[(d0 + i) * 68 + c] = tv[i];
  }
  __syncthreads();
  const float* psf = sf + (size_t)bq * 8192 + hd * 2048;
  bf16x8 sa[2][2];
#pragma unroll
  for (int tm = 0; tm < 2; tm++)
#pragma unroll
    for (int kk = 0; kk < 2; kk++) {
      const float* p = psf + (tm * 16 + l15) * 64 + kk * 32 + quad * 8;
      sa[tm][kk] = pack8(*(const float4*)p, *(const float4*)(p + 4));
    }
  f32x4 acc1[2][4] = {};
#pragma unroll
  for (int kk = 0; kk < 2; kk++) {
#pragma unroll
    for (int tn = 0; tn < 4; tn++) {
      const short* bp = p1T + (tn * 16 + l15) * 68 + kk * 32 + quad * 8;
      short4v lo = *(const short4v*)(const void*)bp;
      short4v hi = *(const short4v*)(const void*)(bp + 4);
      bf16x8 bfr = __builtin_bit_cast(bf16x8, __builtin_shufflevector(lo, hi, 0, 1, 2, 3, 4, 5, 6, 7));
#pragma unroll
      for (int tm = 0; tm < 2; tm++)
        acc1[tm][tn] = __builtin_amdgcn_mfma_f32_16x16x32_bf16(sa[tm][kk], bfr, acc1[tm][tn], 0, 0, 0);
    }
  }
  float s1 = 0.f, s2 = 0.f;
#pragma unroll
  for (int tm = 0; tm < 2; tm++)
#pragma unroll
    for (int tn = 0; tn < 4; tn++)
#pragma unroll
      for (int r = 0; r < 4; r++) {
        float g = gelu_f(acc1[tm][tn][r]);
        acc1[tm][tn][r] = g;
        s1 += g; s2 += g * g;
      }
  wred2(s1, s2);
  float mean = s1 * (1.f / 2048.f);
  float rstd = rsqrtf(fmaxf(s2 * (1.f / 2048.f) - mean * mean, 0.f) + 1e-5f);
#pragma unroll
  for (int tm = 0; tm < 2; tm++)
#pragma unroll
    for (int tn = 0; tn < 4; tn++) {
      short4v o;
#pragma unroll
      for (int r = 0; r < 4; r++) o[r] = f2bf((acc1[tm][tn][r] - mean) * rstd);
      *(short4v*)(void*)(Tl + (tn * 16 + l15) * 40 + tm * 16 + quad * 4) = o;
    }
  __syncthreads();
  const short* pp2 = par + (size_t)bq * 24576 + 16384 + hd * 2048;
  bf16x8 a2[4], b2[4];
#pragma unroll
  for (int t = 0; t < 4; t++) {
    a2[t] = *(const bf16x8*)(const void*)(pp2 + (t * 16 + l15) * 32 + quad * 8);
    b2[t] = *(const bf16x8*)(const void*)(Tl + (t * 16 + l15) * 40 + quad * 8);
  }
  f32x4 acc2[4][4] = {};
#pragma unroll
  for (int tm = 0; tm < 4; tm++)
#pragma unroll
    for (int tn = 0; tn < 4; tn++)
      acc2[tm][tn] = __builtin_amdgcn_mfma_f32_16x16x32_bf16(a2[tm], b2[tn], acc2[tm][tn], 0, 0, 0);
  float u1 = 0.f, u2 = 0.f;
#pragma unroll
  for (int tm = 0; tm < 4; tm++)
#pragma unroll
    for (int tn = 0; tn < 4; tn++)
#pragma unroll
      for (int r = 0; r < 4; r++) {
        float g = gelu_f(acc2[tm][tn][r]);
        acc2[tm][tn][r] = g;
        u1 += g; u2 += g * g;
      }
  wred2(u1, u2);
  float m2 = u1 * (1.f / 4096.f);
  float rs2 = rsqrtf(fmaxf(u2 * (1.f / 4096.f) - m2 * m2, 0.f) + 1e-5f);
  short* pu = U + (size_t)bq * 16384 + hd * 4096;
#pragma unroll
  for (int h2 = 0; h2 < 2; h2++) {
    __syncthreads();
#pragma unroll
    for (int tmh = 0; tmh < 2; tmh++) {
      int tm = h2 * 2 + tmh;
#pragma unroll
      for (int tn = 0; tn < 4; tn++)
#pragma unroll
        for (int r = 0; r < 4; r++) {
          int er = tmh * 16 + quad * 4 + r;
          Tl[er * 72 + tn * 16 + l15] = f2bf((acc2[tm][tn][r] - m2) * rs2);
        }
    }
    __syncthreads();
#pragma unroll
    for (int i = 0; i < 4; i++) {
      int er = i * 8 + (lane >> 3);
      int dch = (lane & 7) * 8;
      uint4 v = *(const uint4*)(const void*)(Tl + er * 72 + dch);
      *(uint4*)(void*)(pu + (size_t)(h2 * 32 + er) * 64 + dch) = v;
    }
  }
}

// ------------- K3x: full-N(256) per block, split-K(16) XCD-local ----------
// U: [nrows][16384] bf16, WT: [256][16384] bf16, C2p: [16][nrows][256] fp32
// grid 912 = 16 seg * 57 bm; seg = b&15 (xcd = b&7), bm = b>>4
__global__ __launch_bounds__(256) void k3x_gemm(const short* __restrict__ U,
                                                const short* __restrict__ WT,
                                                float* __restrict__ C2p,
                                                int nrows) {
  __shared__ short As[64 * 72];
  __shared__ short Bs[256 * 72];
  const int b = blockIdx.x;
  const int seg = b & 15, bm = b >> 4;
  const int tid = threadIdx.x;
  const int lane = tid & 63, wv = tid >> 6;
  const int l15 = lane & 15, quad = lane >> 4;
  const int wn = wv * 64;
  const int sr = tid >> 2, sk = (tid & 3) * 16;
  f32x4 acc[4][4] = {};
  int k0 = seg * 1024;
  for (int kt = 0; kt < 16; kt++, k0 += 64) {
    uint4 a0 = {0, 0, 0, 0}, a1 = {0, 0, 0, 0};
    int gr = bm * 64 + sr;
    if (gr < nrows) {
      const uint4* pa = (const uint4*)(U + (size_t)gr * 16384 + k0 + sk);
      a0 = pa[0]; a1 = pa[1];
    }
    *(uint4*)(As + sr * 72 + sk) = a0;
    *(uint4*)(As + sr * 72 + sk + 8) = a1;
#pragma unroll
    for (int rr = 0; rr < 4; rr++) {
      int br = rr * 64 + sr;
      const uint4* pb = (const uint4*)(WT + (size_t)br * 16384 + k0 + sk);
      *(uint4*)(Bs + br * 72 + sk) = pb[0];
      *(uint4*)(Bs + br * 72 + sk + 8) = pb[1];
    }
    __syncthreads();
#pragma unroll
    for (int kk = 0; kk < 64; kk += 32) {
      bf16x8 af[4], bfr[4];
#pragma unroll
      for (int i = 0; i < 4; i++)
        af[i] = *(const bf16x8*)(const void*)(As + (i * 16 + l15) * 72 + kk + quad * 8);
#pragma unroll
      for (int j = 0; j < 4; j++)
        bfr[j] = *(const bf16x8*)(const void*)(Bs + (wn + j * 16 + l15) * 72 + kk + quad * 8);
#pragma unroll
      for (int i = 0; i < 4; i++)
#pragma unroll
        for (int j = 0; j < 4; j++)
          acc[i][j] = __builtin_amdgcn_mfma_f32_16x16x32_bf16(af[i], bfr[j], acc[i][j], 0, 0, 0);
    }
    __syncthreads();
  }
#pragma unroll
  for (int i = 0; i < 4; i++)
#pragma unroll
    for (int j = 0; j < 4; j++)
#pragma unroll
      for (int r = 0; r < 4; r++) {
        int row = bm * 64 + i * 16 + quad * 4 + r;
        if (row < nrows)
          C2p[((size_t)seg * nrows + row) * 256 + wn + j * 16 + l15] = acc[i][j][r];
      }
}

// ------------- K3: fallback (4-seg, in-kernel W_out transpose) ------------
__global__ __launch_bounds__(256) void k3_gemm(const short* __restrict__ U,
                                               const float* __restrict__ Wo,
                                               float* __restrict__ C2p,
                                               int nrows) {
  __shared__ short As[64 * 72];
  __shared__ short Bs[64 * 72];
  const int tid = threadIdx.x;
  const int bm = blockIdx.x, bn = blockIdx.y, seg = blockIdx.z;
  const int lane = tid & 63, wv = tid >> 6;
  const int l15 = lane & 15, quad = lane >> 4;
  const int wm = (wv & 1) * 32, wn = (wv >> 1) * 32;
  const int sr = tid >> 2, sk = (tid & 3) * 16;
  const int bk = tid >> 2, bn0 = (tid & 3) * 16;
  f32x4 acc[2][2] = {};
  int k0 = seg * 4096;
  for (int kt = 0; kt < 64; kt++, k0 += 64) {
    uint4 a0 = {0, 0, 0, 0}, a1 = {0, 0, 0, 0};
    int gr = bm * 64 + sr;
    if (gr < nrows) {
      const uint4* pa = (const uint4*)(U + (size_t)gr * 16384 + k0 + sk);
      a0 = pa[0]; a1 = pa[1];
    }
    *(uint4*)(As + sr * 72 + sk) = a0;
    *(uint4*)(As + sr * 72 + sk + 8) = a1;
    const float4* pb = (const float4*)(Wo + (size_t)(k0 + bk) * 256 + bn * 64 + bn0);
    float4 b0 = pb[0], b1 = pb[1], b2 = pb[2], b3 = pb[3];
    short* bd = Bs + bn0 * 72 + bk;
    bd[0 * 72] = f2bf(b0.x); bd[1 * 72] = f2bf(b0.y); bd[2 * 72] = f2bf(b0.z); bd[3 * 72] = f2bf(b0.w);
    bd[4 * 72] = f2bf(b1.x); bd[5 * 72] = f2bf(b1.y); bd[6 * 72] = f2bf(b1.z); bd[7 * 72] = f2bf(b1.w);
    bd[8 * 72] = f2bf(b2.x); bd[9 * 72] = f2bf(b2.y); bd[10 * 72] = f2bf(b2.z); bd[11 * 72] = f2bf(b2.w);
    bd[12 * 72] = f2bf(b3.x); bd[13 * 72] = f2bf(b3.y); bd[14 * 72] = f2bf(b3.z); bd[15 * 72] = f2bf(b3.w);
    __syncthreads();
#pragma unroll
    for (int kk = 0; kk < 64; kk += 32) {
      bf16x8 af[2], bfr[2];
#pragma unroll
      for (int i = 0; i < 2; i++)
        af[i] = *(const bf16x8*)(const void*)(As + (wm + i * 16 + l15) * 72 + kk + quad * 8);
#pragma unroll
      for (int j = 0; j < 2; j++)
        bfr[j] = *(const bf16x8*)(const void*)(Bs + (wn + j * 16 + l15) * 72 + kk + quad * 8);
#pragma unroll
      for (int i = 0; i < 2; i++)
#pragma unroll
        for (int j = 0; j < 2; j++)
          acc[i][j] = __builtin_amdgcn_mfma_f32_16x16x32_bf16(af[i], bfr[j], acc[i][j], 0, 0, 0);
    }
    __syncthreads();
  }
#pragma unroll
  for (int i = 0; i < 2; i++)
#pragma unroll
    for (int j = 0; j < 2; j++)
#pragma unroll
      for (int r = 0; r < 4; r++) {
        int row = bm * 64 + wm + i * 16 + quad * 4 + r;
        if (row < nrows)
          C2p[((size_t)seg * nrows + row) * 256 + bn * 64 + wn + j * 16 + l15] = acc[i][j][r];
      }
}

// ------------- K4: reduce nseg partials + b_out + affine LayerNorm --------
__global__ __launch_bounds__(256) void k4_ln(const float* __restrict__ C2p,
                                             const float* __restrict__ bo,
                                             const float* __restrict__ lnw,
                                             const float* __restrict__ lnb,
                                             float* __restrict__ out,
                                             int nrows, int nseg) {
  int row = blockIdx.x * 4 + (threadIdx.x >> 6);
  if (row >= nrows) return;
  int lane = threadIdx.x & 63;
  float v[4] = {0.f, 0.f, 0.f, 0.f};
  for (int s = 0; s < nseg; s++) {
    const float4* p = (const float4*)(C2p + ((size_t)s * nrows + row) * 256) + lane;
    float4 t = *p;
    v[0] += t.x; v[1] += t.y; v[2] += t.z; v[3] += t.w;
  }
  float4 bov = *((const float4*)bo + lane);
  v[0] += bov.x; v[1] += bov.y; v[2] += bov.z; v[3] += bov.w;
  float s1 = v[0] + v[1] + v[2] + v[3];
  float s2 = v[0] * v[0] + v[1] * v[1] + v[2] * v[2] + v[3] * v[3];
  wred2(s1, s2);
  float mean = s1 * (1.f / 256.f);
  float rstd = rsqrtf(fmaxf(s2 * (1.f / 256.f) - mean * mean, 0.f) + 1e-5f);
  float4 wv = *((const float4*)lnw + lane);
  float4 bv = *((const float4*)lnb + lane);
  float4 o;
  o.x = (v[0] - mean) * rstd * wv.x + bv.x;
  o.y = (v[1] - mean) * rstd * wv.y + bv.y;
  o.z = (v[2] - mean) * rstd * wv.z + bv.z;
  o.w = (v[3] - mean) * rstd * wv.w + bv.w;
  *((float4*)(out + (size_t)row * 256) + lane) = o;
}

extern "C" void kernel_launch(void* const* d_in, const int* in_sizes, int n_in,
                              void* d_out, int out_size, void* d_ws, size_t ws_size,
                              hipStream_t stream) {
  const float* qf  = (const float*)d_in[0];
  const float* sf  = (const float*)d_in[1];
  const float* Wg  = (const float*)d_in[2];
  const float* bg  = (const float*)d_in[3];
  const float* Wo  = (const float*)d_in[4];
  const float* bo  = (const float*)d_in[5];
  const float* lnw = (const float*)d_in[6];
  const float* lnb = (const float*)d_in[7];
  char* wsb = (char*)d_ws;

  const size_t sz_WTg = (size_t)24576 * 256 * 2;      //  12.6 MB
  const size_t sz_WTo = (size_t)16384 * 256 * 2;      //   8.4 MB
  const size_t sz_par = (size_t)BQ_TOT * 24576 * 2;   // 176.9 MB
  const size_t sz_U   = (size_t)BQ_TOT * 16384 * 2;   // 118.0 MB
  const size_t sz_Xb  = (size_t)BQ_TOT * 256 * 2;     //   1.8 MB
  const size_t NEED   = sz_WTg + sz_WTo + sz_par + sz_U + sz_Xb;  // 317.7 MB
  // C2p (16*3600*256*4 = 59.0 MB) aliases par (dead after k2)

  if (ws_size >= NEED) {
    short* WTg = (short*)wsb;
    short* WTo = (short*)(wsb + sz_WTg);
    short* par = (short*)(wsb + sz_WTg + sz_WTo);
    short* Uc  = (short*)(wsb + sz_WTg + sz_WTo + sz_par);
    short* Xb  = (short*)(wsb + sz_WTg + sz_WTo + sz_par + sz_U);
    float* C2p = (float*)par;  // alias
    ktrans_f2b<<<dim3(768, 8), 256, 0, stream>>>(Wg, WTg, 256, 24576);
    ktrans_f2b<<<dim3(8, 512), 256, 0, stream>>>(Wo, WTo, 16384, 256);
    kcvt_f2b<<<dim3(450), 256, 0, stream>>>(qf, Xb);
    k1t_gemm<<<dim3(5568), 256, 0, stream>>>(Xb, WTg, bg, par, BQ_TOT);
    k2_mixw<<<dim3(BQ_TOT * 4), 64, 0, stream>>>(sf, par, Uc);
    k3x_gemm<<<dim3(912), 256, 0, stream>>>(Uc, WTo, C2p, BQ_TOT);
    k4_ln<<<dim3(900), 256, 0, stream>>>(C2p, bo, lnw, lnb, (float*)d_out, BQ_TOT, 16);
  } else {
    // chunked fallback: per-row 24576*2 + 16384*2 + 4*256*4 = 86016 B
    const size_t per_row = 86016;
    long long chunk_ll = (long long)(ws_size / per_row);
    int chunk = (chunk_ll > BQ_TOT) ? BQ_TOT : (int)chunk_ll;
    if (chunk < 8) chunk = 8;
    short* par = (short*)wsb;
    short* Uc  = (short*)(wsb + (size_t)chunk * 24576 * 2);
    float* C2p = (float*)(wsb + (size_t)chunk * 24576 * 2 + (size_t)chunk * 16384 * 2);
    for (int rb = 0; rb < BQ_TOT; rb += chunk) {
      int r = (BQ_TOT - rb < chunk) ? (BQ_TOT - rb) : chunk;
      k1_gemm<<<dim3((r + 127) / 128, 192), 256, 0, stream>>>(
          qf + (size_t)rb * 256, Wg, bg, par, r);
      k2_mixw<<<dim3(r * 4), 64, 0, stream>>>(sf + (size_t)rb * 8192, par, Uc);
      k3_gemm<<<dim3((r + 63) / 64, 4, 4), 256, 0, stream>>>(Uc, Wo, C2p, r);
      k4_ln<<<dim3((r + 3) / 4), 256, 0, stream>>>(
          C2p, bo, lnw, lnb, (float*)d_out + (size_t)rb * 256, r, 4);
    }
  }
}

// Round 8
// 446.278 us; speedup vs baseline: 1.1453x; 1.0207x over previous
//
#include <hip/hip_runtime.h>
#include <hip/hip_bf16.h>

// FeatureMixer on MI355X — R8.
// R7 post-mortem: k1t latency-exposed (all pipes <25%). Changes:
// (1) k1t K-loop register-prefetch pipeline (loads for kt+1 issued before
//     MFMAs of kt -> L2 latency hidden under compute).
// (2) p1 stored pre-transposed in par: ktrans permutes W_gen^T rows
//     (sigma: hd,c,d -> hd,d,c) + bias permuted; k2 loads p1 B-frags
//     directly from global (no LDS transpose).

typedef __attribute__((ext_vector_type(8))) __bf16 bf16x8;
typedef __attribute__((ext_vector_type(4))) float f32x4;
typedef __attribute__((ext_vector_type(4))) short short4v;
typedef __attribute__((ext_vector_type(8))) short short8v;

#define BQ_TOT 3600

__device__ __forceinline__ short f2bf(float f) {
  __hip_bfloat16 h = __float2bfloat16(f);
  short s; __builtin_memcpy(&s, &h, 2);
  return s;
}
__device__ __forceinline__ bf16x8 pack8(float4 a, float4 b) {
  short8v o;
  o[0] = f2bf(a.x); o[1] = f2bf(a.y); o[2] = f2bf(a.z); o[3] = f2bf(a.w);
  o[4] = f2bf(b.x); o[5] = f2bf(b.y); o[6] = f2bf(b.z); o[7] = f2bf(b.w);
  return __builtin_bit_cast(bf16x8, o);
}
__device__ __forceinline__ float gelu_f(float x) {
  float x2 = x * x;
  float u = x * (0.7978845608f + 0.0356774081f * x2);
  float e = __builtin_amdgcn_exp2f(u * 2.885390082f);
  float t = 1.0f - 2.0f / (e + 1.0f);
  return 0.5f * x * (1.0f + t);
}
__device__ __forceinline__ void wred2(float& a, float& b) {
#pragma unroll
  for (int m = 32; m >= 1; m >>= 1) {
    a += __shfl_xor(a, m, 64);
    b += __shfl_xor(b, m, 64);
  }
}

// ------------- kcvt: fp32 -> bf16 flat ------------------------------------
__global__ __launch_bounds__(256) void kcvt_f2b(const float* __restrict__ in,
                                                short* __restrict__ out) {
  int idx = (blockIdx.x * 256 + threadIdx.x) * 8;
  const float4* p = (const float4*)(in + idx);
  *(short8v*)(void*)(out + idx) = __builtin_bit_cast(short8v, pack8(p[0], p[1]));
}

// ------------- kperm_bg: permuted bias copy (p1 region sigma) -------------
__global__ __launch_bounds__(256) void kperm_bg(const float* __restrict__ bg,
                                                float* __restrict__ bgp) {
  int p = blockIdx.x * 256 + threadIdx.x;
  int src = p;
  if (p < 16384) {
    int r = p & 4095;
    src = (p & ~4095) + ((r & 63) << 6) + (r >> 6);
  }
  bgp[p] = bg[src];
}

// ------------- transpose fp32 [R][C] -> bf16 [C][R], opt p1-permute -------
__global__ __launch_bounds__(256) void ktrans_f2b(const float* __restrict__ in,
                                                  short* __restrict__ out,
                                                  int R, int C, int permute_p1) {
  __shared__ float t[32][33];
  int tx = threadIdx.x & 31, ty = threadIdx.x >> 5;  // 32 x 8
  int r0 = blockIdx.y * 32, c0 = blockIdx.x * 32;
#pragma unroll
  for (int i = 0; i < 4; i++)
    t[ty + i * 8][tx] = in[(size_t)(r0 + ty + i * 8) * C + c0 + tx];
  __syncthreads();
#pragma unroll
  for (int i = 0; i < 4; i++) {
    int oc = c0 + ty + i * 8;  // original output row (par column)
    int orow = oc;
    if (permute_p1 && oc < 16384) {
      int r = oc & 4095;
      orow = (oc & ~4095) + ((r & 63) << 6) + (r >> 6);
    }
    out[(size_t)orow * R + r0 + tx] = f2bf(t[tx][ty + i * 8]);
  }
}

// ------------- K1t: par = Xb @ W_gen + bgp; XCD-local ct; reg-prefetch ----
// Xb: [nrows][256] bf16, WT: [24576][256] bf16 (rows sigma-permuted),
// par: [nrows][24576] bf16, bgp: permuted fp32 bias
__global__ __launch_bounds__(256) void k1t_gemm(const short* __restrict__ Xb,
                                                const short* __restrict__ WT,
                                                const float* __restrict__ bgp,
                                                short* __restrict__ par,
                                                int nrows) {
  __shared__ short smem[128 * 40 * 2];  // As | Bs ; aliased as Cs in epilogue
  short* As = smem;
  short* Bs = smem + 128 * 40;
  const int b = blockIdx.x;
  const int xcd = b & 7, i = b >> 3;
  const int ct = xcd * 24 + i / 29;
  const int rt = i % 29;
  const int tid = threadIdx.x;
  const int lane = tid & 63, wv = tid >> 6;
  const int l15 = lane & 15, quad = lane >> 4;
  const int wm = (wv & 1) * 64, wn = (wv >> 1) * 64;
  const int sm = tid >> 1, sk = (tid & 1) * 16;
  const int gr = rt * 128 + sm;
  const bool av = gr < nrows;
  const uint4* paB = (const uint4*)(Xb + (size_t)gr * 256 + sk);
  const uint4* pbB = (const uint4*)(WT + (size_t)(ct * 128 + sm) * 256 + sk);
  uint4 a0 = {0, 0, 0, 0}, a1 = {0, 0, 0, 0}, b0, b1;
  if (av) { a0 = paB[0]; a1 = paB[1]; }
  b0 = pbB[0]; b1 = pbB[1];
  f32x4 acc[4][4] = {};
#pragma unroll
  for (int kt = 0; kt < 8; kt++) {
    *(uint4*)(As + sm * 40 + sk) = a0;
    *(uint4*)(As + sm * 40 + sk + 8) = a1;
    *(uint4*)(Bs + sm * 40 + sk) = b0;
    *(uint4*)(Bs + sm * 40 + sk + 8) = b1;
    __syncthreads();
    if (kt < 7) {  // prefetch next tile; latency hidden under MFMAs below
      const uint4* pa = paB + (kt + 1) * 4;
      const uint4* pb = pbB + (kt + 1) * 4;
      if (av) { a0 = pa[0]; a1 = pa[1]; }
      b0 = pb[0]; b1 = pb[1];
    }
    bf16x8 af[4], bfr[4];
#pragma unroll
    for (int i2 = 0; i2 < 4; i2++)
      af[i2] = *(const bf16x8*)(const void*)(As + (wm + i2 * 16 + l15) * 40 + quad * 8);
#pragma unroll
    for (int j = 0; j < 4; j++)
      bfr[j] = *(const bf16x8*)(const void*)(Bs + (wn + j * 16 + l15) * 40 + quad * 8);
#pragma unroll
    for (int i2 = 0; i2 < 4; i2++)
#pragma unroll
      for (int j = 0; j < 4; j++)
        acc[i2][j] = __builtin_amdgcn_mfma_f32_16x16x32_bf16(af[i2], bfr[j], acc[i2][j], 0, 0, 0);
    __syncthreads();
  }
  // epilogue: restage through LDS, full-line streaming stores
  short* Cs = smem;  // 64 x 136 shorts
#pragma unroll
  for (int h = 0; h < 2; h++) {
    if ((wv & 1) == h) {
#pragma unroll
      for (int i2 = 0; i2 < 4; i2++)
#pragma unroll
        for (int j = 0; j < 4; j++) {
          float bgv = bgp[ct * 128 + wn + j * 16 + l15];
#pragma unroll
          for (int r = 0; r < 4; r++)
            Cs[(i2 * 16 + quad * 4 + r) * 136 + wn + j * 16 + l15] =
                f2bf(acc[i2][j][r] + bgv);
        }
    }
    __syncthreads();
#pragma unroll
    for (int it = 0; it < 4; it++) {
      int rr = it * 16 + (tid >> 4);
      int cc = (tid & 15) * 8;
      uint4 v = *(const uint4*)(const void*)(Cs + rr * 136 + cc);
      int row = rt * 128 + h * 64 + rr;
      if (row < nrows)
        *(uint4*)(par + (size_t)row * 24576 + ct * 128 + cc) = v;
    }
    __syncthreads();
  }
}

// ------------- K1: fallback (in-kernel W_gen transpose, fp32 X, no perm) --
__global__ __launch_bounds__(256) void k1_gemm(const float* __restrict__ X,
                                               const float* __restrict__ Wg,
                                               const float* __restrict__ bg,
                                               short* __restrict__ par,
                                               int nrows) {
  __shared__ short As[128 * 40];
  __shared__ short Bs[128 * 40];
  const int tid = threadIdx.x;
  const int rt = blockIdx.x, ct = blockIdx.y;
  const int lane = tid & 63, wv = tid >> 6;
  const int l15 = lane & 15, quad = lane >> 4;
  const int wm = (wv & 1) * 64, wn = (wv >> 1) * 64;
  const int sm = tid >> 1, sk = (tid & 1) * 16;
  const int bk = tid >> 3, bn0 = (tid & 7) * 16;
  f32x4 acc[4][4] = {};
  for (int k0 = 0; k0 < 256; k0 += 32) {
    float4 av[4] = {};
    int gr = rt * 128 + sm;
    if (gr < nrows) {
      const float4* pa = (const float4*)(X + (size_t)gr * 256 + k0 + sk);
      av[0] = pa[0]; av[1] = pa[1]; av[2] = pa[2]; av[3] = pa[3];
    }
    *(short8v*)(void*)(As + sm * 40 + sk) = __builtin_bit_cast(short8v, pack8(av[0], av[1]));
    *(short8v*)(void*)(As + sm * 40 + sk + 8) = __builtin_bit_cast(short8v, pack8(av[2], av[3]));
    const float4* pb = (const float4*)(Wg + (size_t)(k0 + bk) * 24576 + ct * 128 + bn0);
    float4 b0 = pb[0], b1 = pb[1], b2 = pb[2], b3 = pb[3];
    short* bd = Bs + bn0 * 40 + bk;
    bd[0 * 40] = f2bf(b0.x); bd[1 * 40] = f2bf(b0.y); bd[2 * 40] = f2bf(b0.z); bd[3 * 40] = f2bf(b0.w);
    bd[4 * 40] = f2bf(b1.x); bd[5 * 40] = f2bf(b1.y); bd[6 * 40] = f2bf(b1.z); bd[7 * 40] = f2bf(b1.w);
    bd[8 * 40] = f2bf(b2.x); bd[9 * 40] = f2bf(b2.y); bd[10 * 40] = f2bf(b2.z); bd[11 * 40] = f2bf(b2.w);
    bd[12 * 40] = f2bf(b3.x); bd[13 * 40] = f2bf(b3.y); bd[14 * 40] = f2bf(b3.z); bd[15 * 40] = f2bf(b3.w);
    __syncthreads();
    bf16x8 af[4], bfr[4];
#pragma unroll
    for (int i = 0; i < 4; i++)
      af[i] = *(const bf16x8*)(const void*)(As + (wm + i * 16 + l15) * 40 + quad * 8);
#pragma unroll
    for (int j = 0; j < 4; j++)
      bfr[j] = *(const bf16x8*)(const void*)(Bs + (wn + j * 16 + l15) * 40 + quad * 8);
#pragma unroll
    for (int i = 0; i < 4; i++)
#pragma unroll
      for (int j = 0; j < 4; j++)
        acc[i][j] = __builtin_amdgcn_mfma_f32_16x16x32_bf16(af[i], bfr[j], acc[i][j], 0, 0, 0);
    __syncthreads();
  }
#pragma unroll
  for (int i = 0; i < 4; i++) {
#pragma unroll
    for (int j = 0; j < 4; j++) {
      int col = ct * 128 + wn + j * 16 + l15;
      float bgv = bg[col];
#pragma unroll
      for (int r = 0; r < 4; r++) {
        int row = rt * 128 + wm + i * 16 + quad * 4 + r;
        if (row < nrows)
          par[(size_t)row * 24576 + col] = f2bf(acc[i][j][r] + bgv);
      }
    }
  }
}

// ------------- K2n: one wave per (bq, head); p1 pre-transposed ------------
__global__ __launch_bounds__(64, 3) void k2_mixn(const float* __restrict__ sf,
                                                 const short* __restrict__ par,
                                                 short* __restrict__ U) {
  __shared__ short Tl[64 * 40];   // [d][p] stage; reused as U-stage [32][72]
  const int bq = blockIdx.x >> 2, hd = blockIdx.x & 3;
  const int lane = threadIdx.x & 63;
  const int l15 = lane & 15, quad = lane >> 4;
  const short* pp1 = par + (size_t)bq * 24576 + hd * 4096;  // physical [d][c]
  const float* psf = sf + (size_t)bq * 8192 + hd * 2048;
  bf16x8 sa[2][2];
#pragma unroll
  for (int tm = 0; tm < 2; tm++)
#pragma unroll
    for (int kk = 0; kk < 2; kk++) {
      const float* p = psf + (tm * 16 + l15) * 64 + kk * 32 + quad * 8;
      sa[tm][kk] = pack8(*(const float4*)p, *(const float4*)(p + 4));
    }
  bf16x8 b1[4][2];
#pragma unroll
  for (int tn = 0; tn < 4; tn++)
#pragma unroll
    for (int kk = 0; kk < 2; kk++)
      b1[tn][kk] = *(const bf16x8*)(const void*)(pp1 + (tn * 16 + l15) * 64 + kk * 32 + quad * 8);
  f32x4 acc1[2][4] = {};
#pragma unroll
  for (int kk = 0; kk < 2; kk++)
#pragma unroll
    for (int tn = 0; tn < 4; tn++)
#pragma unroll
      for (int tm = 0; tm < 2; tm++)
        acc1[tm][tn] = __builtin_amdgcn_mfma_f32_16x16x32_bf16(sa[tm][kk], b1[tn][kk], acc1[tm][tn], 0, 0, 0);
  float s1 = 0.f, s2 = 0.f;
#pragma unroll
  for (int tm = 0; tm < 2; tm++)
#pragma unroll
    for (int tn = 0; tn < 4; tn++)
#pragma unroll
      for (int r = 0; r < 4; r++) {
        float g = gelu_f(acc1[tm][tn][r]);
        acc1[tm][tn][r] = g;
        s1 += g; s2 += g * g;
      }
  wred2(s1, s2);
  float mean = s1 * (1.f / 2048.f);
  float rstd = rsqrtf(fmaxf(s2 * (1.f / 2048.f) - mean * mean, 0.f) + 1e-5f);
#pragma unroll
  for (int tm = 0; tm < 2; tm++)
#pragma unroll
    for (int tn = 0; tn < 4; tn++) {
      short4v o;
#pragma unroll
      for (int r = 0; r < 4; r++) o[r] = f2bf((acc1[tm][tn][r] - mean) * rstd);
      *(short4v*)(void*)(Tl + (tn * 16 + l15) * 40 + tm * 16 + quad * 4) = o;
    }
  __syncthreads();
  const short* pp2 = par + (size_t)bq * 24576 + 16384 + hd * 2048;
  bf16x8 a2[4], b2[4];
#pragma unroll
  for (int t = 0; t < 4; t++) {
    a2[t] = *(const bf16x8*)(const void*)(pp2 + (t * 16 + l15) * 32 + quad * 8);
    b2[t] = *(const bf16x8*)(const void*)(Tl + (t * 16 + l15) * 40 + quad * 8);
  }
  f32x4 acc2[4][4] = {};
#pragma unroll
  for (int tm = 0; tm < 4; tm++)
#pragma unroll
    for (int tn = 0; tn < 4; tn++)
      acc2[tm][tn] = __builtin_amdgcn_mfma_f32_16x16x32_bf16(a2[tm], b2[tn], acc2[tm][tn], 0, 0, 0);
  float u1 = 0.f, u2 = 0.f;
#pragma unroll
  for (int tm = 0; tm < 4; tm++)
#pragma unroll
    for (int tn = 0; tn < 4; tn++)
#pragma unroll
      for (int r = 0; r < 4; r++) {
        float g = gelu_f(acc2[tm][tn][r]);
        acc2[tm][tn][r] = g;
        u1 += g; u2 += g * g;
      }
  wred2(u1, u2);
  float m2 = u1 * (1.f / 4096.f);
  float rs2 = rsqrtf(fmaxf(u2 * (1.f / 4096.f) - m2 * m2, 0.f) + 1e-5f);
  short* pu = U + (size_t)bq * 16384 + hd * 4096;
#pragma unroll
  for (int h2 = 0; h2 < 2; h2++) {
    __syncthreads();
#pragma unroll
    for (int tmh = 0; tmh < 2; tmh++) {
      int tm = h2 * 2 + tmh;
#pragma unroll
      for (int tn = 0; tn < 4; tn++)
#pragma unroll
        for (int r = 0; r < 4; r++) {
          int er = tmh * 16 + quad * 4 + r;
          Tl[er * 72 + tn * 16 + l15] = f2bf((acc2[tm][tn][r] - m2) * rs2);
        }
    }
    __syncthreads();
#pragma unroll
    for (int i = 0; i < 4; i++) {
      int er = i * 8 + (lane >> 3);
      int dch = (lane & 7) * 8;
      uint4 v = *(const uint4*)(const void*)(Tl + er * 72 + dch);
      *(uint4*)(void*)(pu + (size_t)(h2 * 32 + er) * 64 + dch) = v;
    }
  }
}

// ------------- K2w: fallback (p1 in original [c][d] layout) ---------------
__global__ __launch_bounds__(64, 3) void k2_mixw(const float* __restrict__ sf,
                                                 const short* __restrict__ par,
                                                 short* __restrict__ U) {
  __shared__ short p1T[64 * 68];
  __shared__ short Tl[64 * 40];
  const int bq = blockIdx.x >> 2, hd = blockIdx.x & 3;
  const int lane = threadIdx.x & 63;
  const int l15 = lane & 15, quad = lane >> 4;
  const short* pp1 = par + (size_t)bq * 24576 + hd * 4096;
#pragma unroll
  for (int it = 0; it < 8; it++) {
    int c = it * 8 + (lane >> 3);
    int d0 = (lane & 7) * 8;
    short8v tv = *(const short8v*)(const void*)(pp1 + c * 64 + d0);
#pragma unroll
    for (int i = 0; i < 8; i++) p1T[(d0 + i) * 68 + c] = tv[i];
  }
  __syncthreads();
  const float* psf = sf + (size_t)bq * 8192 + hd * 2048;
  bf16x8 sa[2][2];
#pragma unroll
  for (int tm = 0; tm < 2; tm++)
#pragma unroll
    for (int kk = 0; kk < 2; kk++) {
      const float* p = psf + (tm * 16 + l15) * 64 + kk * 32 + quad * 8;
      sa[tm][kk] = pack8(*(const float4*)p, *(const float4*)(p + 4));
    }
  f32x4 acc1[2][4] = {};
#pragma unroll
  for (int kk = 0; kk < 2; kk++) {
#pragma unroll
    for (int tn = 0; tn < 4; tn++) {
      const short* bp = p1T + (tn * 16 + l15) * 68 + kk * 32 + quad * 8;
      short4v lo = *(const short4v*)(const void*)bp;
      short4v hi = *(const short4v*)(const void*)(bp + 4);
      bf16x8 bfr = __builtin_bit_cast(bf16x8, __builtin_shufflevector(lo, hi, 0, 1, 2, 3, 4, 5, 6, 7));
#pragma unroll
      for (int tm = 0; tm < 2; tm++)
        acc1[tm][tn] = __builtin_amdgcn_mfma_f32_16x16x32_bf16(sa[tm][kk], bfr, acc1[tm][tn], 0, 0, 0);
    }
  }
  float s1 = 0.f, s2 = 0.f;
#pragma unroll
  for (int tm = 0; tm < 2; tm++)
#pragma unroll
    for (int tn = 0; tn < 4; tn++)
#pragma unroll
      for (int r = 0; r < 4; r++) {
        float g = gelu_f(acc1[tm][tn][r]);
        acc1[tm][tn][r] = g;
        s1 += g; s2 += g * g;
      }
  wred2(s1, s2);
  float mean = s1 * (1.f / 2048.f);
  float rstd = rsqrtf(fmaxf(s2 * (1.f / 2048.f) - mean * mean, 0.f) + 1e-5f);
#pragma unroll
  for (int tm = 0; tm < 2; tm++)
#pragma unroll
    for (int tn = 0; tn < 4; tn++) {
      short4v o;
#pragma unroll
      for (int r = 0; r < 4; r++) o[r] = f2bf((acc1[tm][tn][r] - mean) * rstd);
      *(short4v*)(void*)(Tl + (tn * 16 + l15) * 40 + tm * 16 + quad * 4) = o;
    }
  __syncthreads();
  const short* pp2 = par + (size_t)bq * 24576 + 16384 + hd * 2048;
  bf16x8 a2[4], b2[4];
#pragma unroll
  for (int t = 0; t < 4; t++) {
    a2[t] = *(const bf16x8*)(const void*)(pp2 + (t * 16 + l15) * 32 + quad * 8);
    b2[t] = *(const bf16x8*)(const void*)(Tl + (t * 16 + l15) * 40 + quad * 8);
  }
  f32x4 acc2[4][4] = {};
#pragma unroll
  for (int tm = 0; tm < 4; tm++)
#pragma unroll
    for (int tn = 0; tn < 4; tn++)
      acc2[tm][tn] = __builtin_amdgcn_mfma_f32_16x16x32_bf16(a2[tm], b2[tn], acc2[tm][tn], 0, 0, 0);
  float u1 = 0.f, u2 = 0.f;
#pragma unroll
  for (int tm = 0; tm < 4; tm++)
#pragma unroll
    for (int tn = 0; tn < 4; tn++)
#pragma unroll
      for (int r = 0; r < 4; r++) {
        float g = gelu_f(acc2[tm][tn][r]);
        acc2[tm][tn][r] = g;
        u1 += g; u2 += g * g;
      }
  wred2(u1, u2);
  float m2 = u1 * (1.f / 4096.f);
  float rs2 = rsqrtf(fmaxf(u2 * (1.f / 4096.f) - m2 * m2, 0.f) + 1e-5f);
  short* pu = U + (size_t)bq * 16384 + hd * 4096;
#pragma unroll
  for (int h2 = 0; h2 < 2; h2++) {
    __syncthreads();
#pragma unroll
    for (int tmh = 0; tmh < 2; tmh++) {
      int tm = h2 * 2 + tmh;
#pragma unroll
      for (int tn = 0; tn < 4; tn++)
#pragma unroll
        for (int r = 0; r < 4; r++) {
          int er = tmh * 16 + quad * 4 + r;
          Tl[er * 72 + tn * 16 + l15] = f2bf((acc2[tm][tn][r] - m2) * rs2);
        }
    }
    __syncthreads();
#pragma unroll
    for (int i = 0; i < 4; i++) {
      int er = i * 8 + (lane >> 3);
      int dch = (lane & 7) * 8;
      uint4 v = *(const uint4*)(const void*)(Tl + er * 72 + dch);
      *(uint4*)(void*)(pu + (size_t)(h2 * 32 + er) * 64 + dch) = v;
    }
  }
}

// ------------- K3x: full-N(256) per block, split-K(16) XCD-local ----------
__global__ __launch_bounds__(256) void k3x_gemm(const short* __restrict__ U,
                                                const short* __restrict__ WT,
                                                float* __restrict__ C2p,
                                                int nrows) {
  __shared__ short As[64 * 72];
  __shared__ short Bs[256 * 72];
  const int b = blockIdx.x;
  const int seg = b & 15, bm = b >> 4;
  const int tid = threadIdx.x;
  const int lane = tid & 63, wv = tid >> 6;
  const int l15 = lane & 15, quad = lane >> 4;
  const int wn = wv * 64;
  const int sr = tid >> 2, sk = (tid & 3) * 16;
  f32x4 acc[4][4] = {};
  int k0 = seg * 1024;
  for (int kt = 0; kt < 16; kt++, k0 += 64) {
    uint4 a0 = {0, 0, 0, 0}, a1 = {0, 0, 0, 0};
    int gr = bm * 64 + sr;
    if (gr < nrows) {
      const uint4* pa = (const uint4*)(U + (size_t)gr * 16384 + k0 + sk);
      a0 = pa[0]; a1 = pa[1];
    }
    *(uint4*)(As + sr * 72 + sk) = a0;
    *(uint4*)(As + sr * 72 + sk + 8) = a1;
#pragma unroll
    for (int rr = 0; rr < 4; rr++) {
      int br = rr * 64 + sr;
      const uint4* pb = (const uint4*)(WT + (size_t)br * 16384 + k0 + sk);
      *(uint4*)(Bs + br * 72 + sk) = pb[0];
      *(uint4*)(Bs + br * 72 + sk + 8) = pb[1];
    }
    __syncthreads();
#pragma unroll
    for (int kk = 0; kk < 64; kk += 32) {
      bf16x8 af[4], bfr[4];
#pragma unroll
      for (int i = 0; i < 4; i++)
        af[i] = *(const bf16x8*)(const void*)(As + (i * 16 + l15) * 72 + kk + quad * 8);
#pragma unroll
      for (int j = 0; j < 4; j++)
        bfr[j] = *(const bf16x8*)(const void*)(Bs + (wn + j * 16 + l15) * 72 + kk + quad * 8);
#pragma unroll
      for (int i = 0; i < 4; i++)
#pragma unroll
        for (int j = 0; j < 4; j++)
          acc[i][j] = __builtin_amdgcn_mfma_f32_16x16x32_bf16(af[i], bfr[j], acc[i][j], 0, 0, 0);
    }
    __syncthreads();
  }
#pragma unroll
  for (int i = 0; i < 4; i++)
#pragma unroll
    for (int j = 0; j < 4; j++)
#pragma unroll
      for (int r = 0; r < 4; r++) {
        int row = bm * 64 + i * 16 + quad * 4 + r;
        if (row < nrows)
          C2p[((size_t)seg * nrows + row) * 256 + wn + j * 16 + l15] = acc[i][j][r];
      }
}

// ------------- K3: fallback (4-seg, in-kernel W_out transpose) ------------
__global__ __launch_bounds__(256) void k3_gemm(const short* __restrict__ U,
                                               const float* __restrict__ Wo,
                                               float* __restrict__ C2p,
                                               int nrows) {
  __shared__ short As[64 * 72];
  __shared__ short Bs[64 * 72];
  const int tid = threadIdx.x;
  const int bm = blockIdx.x, bn = blockIdx.y, seg = blockIdx.z;
  const int lane = tid & 63, wv = tid >> 6;
  const int l15 = lane & 15, quad = lane >> 4;
  const int wm = (wv & 1) * 32, wn = (wv >> 1) * 32;
  const int sr = tid >> 2, sk = (tid & 3) * 16;
  const int bk = tid >> 2, bn0 = (tid & 3) * 16;
  f32x4 acc[2][2] = {};
  int k0 = seg * 4096;
  for (int kt = 0; kt < 64; kt++, k0 += 64) {
    uint4 a0 = {0, 0, 0, 0}, a1 = {0, 0, 0, 0};
    int gr = bm * 64 + sr;
    if (gr < nrows) {
      const uint4* pa = (const uint4*)(U + (size_t)gr * 16384 + k0 + sk);
      a0 = pa[0]; a1 = pa[1];
    }
    *(uint4*)(As + sr * 72 + sk) = a0;
    *(uint4*)(As + sr * 72 + sk + 8) = a1;
    const float4* pb = (const float4*)(Wo + (size_t)(k0 + bk) * 256 + bn * 64 + bn0);
    float4 b0 = pb[0], b1 = pb[1], b2 = pb[2], b3 = pb[3];
    short* bd = Bs + bn0 * 72 + bk;
    bd[0 * 72] = f2bf(b0.x); bd[1 * 72] = f2bf(b0.y); bd[2 * 72] = f2bf(b0.z); bd[3 * 72] = f2bf(b0.w);
    bd[4 * 72] = f2bf(b1.x); bd[5 * 72] = f2bf(b1.y); bd[6 * 72] = f2bf(b1.z); bd[7 * 72] = f2bf(b1.w);
    bd[8 * 72] = f2bf(b2.x); bd[9 * 72] = f2bf(b2.y); bd[10 * 72] = f2bf(b2.z); bd[11 * 72] = f2bf(b2.w);
    bd[12 * 72] = f2bf(b3.x); bd[13 * 72] = f2bf(b3.y); bd[14 * 72] = f2bf(b3.z); bd[15 * 72] = f2bf(b3.w);
    __syncthreads();
#pragma unroll
    for (int kk = 0; kk < 64; kk += 32) {
      bf16x8 af[2], bfr[2];
#pragma unroll
      for (int i = 0; i < 2; i++)
        af[i] = *(const bf16x8*)(const void*)(As + (wm + i * 16 + l15) * 72 + kk + quad * 8);
#pragma unroll
      for (int j = 0; j < 2; j++)
        bfr[j] = *(const bf16x8*)(const void*)(Bs + (wn + j * 16 + l15) * 72 + kk + quad * 8);
#pragma unroll
      for (int i = 0; i < 2; i++)
#pragma unroll
        for (int j = 0; j < 2; j++)
          acc[i][j] = __builtin_amdgcn_mfma_f32_16x16x32_bf16(af[i], bfr[j], acc[i][j], 0, 0, 0);
    }
    __syncthreads();
  }
#pragma unroll
  for (int i = 0; i < 2; i++)
#pragma unroll
    for (int j = 0; j < 2; j++)
#pragma unroll
      for (int r = 0; r < 4; r++) {
        int row = bm * 64 + wm + i * 16 + quad * 4 + r;
        if (row < nrows)
          C2p[((size_t)seg * nrows + row) * 256 + bn * 64 + wn + j * 16 + l15] = acc[i][j][r];
      }
}

// ------------- K4: reduce nseg partials + b_out + affine LayerNorm --------
__global__ __launch_bounds__(256) void k4_ln(const float* __restrict__ C2p,
                                             const float* __restrict__ bo,
                                             const float* __restrict__ lnw,
                                             const float* __restrict__ lnb,
                                             float* __restrict__ out,
                                             int nrows, int nseg) {
  int row = blockIdx.x * 4 + (threadIdx.x >> 6);
  if (row >= nrows) return;
  int lane = threadIdx.x & 63;
  float v[4] = {0.f, 0.f, 0.f, 0.f};
  for (int s = 0; s < nseg; s++) {
    const float4* p = (const float4*)(C2p + ((size_t)s * nrows + row) * 256) + lane;
    float4 t = *p;
    v[0] += t.x; v[1] += t.y; v[2] += t.z; v[3] += t.w;
  }
  float4 bov = *((const float4*)bo + lane);
  v[0] += bov.x; v[1] += bov.y; v[2] += bov.z; v[3] += bov.w;
  float s1 = v[0] + v[1] + v[2] + v[3];
  float s2 = v[0] * v[0] + v[1] * v[1] + v[2] * v[2] + v[3] * v[3];
  wred2(s1, s2);
  float mean = s1 * (1.f / 256.f);
  float rstd = rsqrtf(fmaxf(s2 * (1.f / 256.f) - mean * mean, 0.f) + 1e-5f);
  float4 wv = *((const float4*)lnw + lane);
  float4 bv = *((const float4*)lnb + lane);
  float4 o;
  o.x = (v[0] - mean) * rstd * wv.x + bv.x;
  o.y = (v[1] - mean) * rstd * wv.y + bv.y;
  o.z = (v[2] - mean) * rstd * wv.z + bv.z;
  o.w = (v[3] - mean) * rstd * wv.w + bv.w;
  *((float4*)(out + (size_t)row * 256) + lane) = o;
}

extern "C" void kernel_launch(void* const* d_in, const int* in_sizes, int n_in,
                              void* d_out, int out_size, void* d_ws, size_t ws_size,
                              hipStream_t stream) {
  const float* qf  = (const float*)d_in[0];
  const float* sf  = (const float*)d_in[1];
  const float* Wg  = (const float*)d_in[2];
  const float* bg  = (const float*)d_in[3];
  const float* Wo  = (const float*)d_in[4];
  const float* bo  = (const float*)d_in[5];
  const float* lnw = (const float*)d_in[6];
  const float* lnb = (const float*)d_in[7];
  char* wsb = (char*)d_ws;

  const size_t sz_WTg = (size_t)24576 * 256 * 2;      //  12.6 MB
  const size_t sz_WTo = (size_t)16384 * 256 * 2;      //   8.4 MB
  const size_t sz_par = (size_t)BQ_TOT * 24576 * 2;   // 176.9 MB
  const size_t sz_U   = (size_t)BQ_TOT * 16384 * 2;   // 118.0 MB
  const size_t sz_Xb  = (size_t)BQ_TOT * 256 * 2;     //   1.8 MB
  const size_t sz_bgp = (size_t)24576 * 4;            //  98 KB
  const size_t NEED   = sz_WTg + sz_WTo + sz_par + sz_U + sz_Xb + sz_bgp;
  // C2p (16*3600*256*4 = 59.0 MB) aliases par (dead after k2)

  if (ws_size >= NEED) {
    short* WTg = (short*)wsb;
    short* WTo = (short*)(wsb + sz_WTg);
    short* par = (short*)(wsb + sz_WTg + sz_WTo);
    short* Uc  = (short*)(wsb + sz_WTg + sz_WTo + sz_par);
    short* Xb  = (short*)(wsb + sz_WTg + sz_WTo + sz_par + sz_U);
    float* bgp = (float*)(wsb + sz_WTg + sz_WTo + sz_par + sz_U + sz_Xb);
    float* C2p = (float*)par;  // alias
    ktrans_f2b<<<dim3(768, 8), 256, 0, stream>>>(Wg, WTg, 256, 24576, 1);
    ktrans_f2b<<<dim3(8, 512), 256, 0, stream>>>(Wo, WTo, 16384, 256, 0);
    kcvt_f2b<<<dim3(450), 256, 0, stream>>>(qf, Xb);
    kperm_bg<<<dim3(96), 256, 0, stream>>>(bg, bgp);
    k1t_gemm<<<dim3(5568), 256, 0, stream>>>(Xb, WTg, bgp, par, BQ_TOT);
    k2_mixn<<<dim3(BQ_TOT * 4), 64, 0, stream>>>(sf, par, Uc);
    k3x_gemm<<<dim3(912), 256, 0, stream>>>(Uc, WTo, C2p, BQ_TOT);
    k4_ln<<<dim3(900), 256, 0, stream>>>(C2p, bo, lnw, lnb, (float*)d_out, BQ_TOT, 16);
  } else {
    const size_t per_row = 86016;
    long long chunk_ll = (long long)(ws_size / per_row);
    int chunk = (chunk_ll > BQ_TOT) ? BQ_TOT : (int)chunk_ll;
    if (chunk < 8) chunk = 8;
    short* par = (short*)wsb;
    short* Uc  = (short*)(wsb + (size_t)chunk * 24576 * 2);
    float* C2p = (float*)(wsb + (size_t)chunk * 24576 * 2 + (size_t)chunk * 16384 * 2);
    for (int rb = 0; rb < BQ_TOT; rb += chunk) {
      int r = (BQ_TOT - rb < chunk) ? (BQ_TOT - rb) : chunk;
      k1_gemm<<<dim3((r + 127) / 128, 192), 256, 0, stream>>>(
          qf + (size_t)rb * 256, Wg, bg, par, r);
      k2_mixw<<<dim3(r * 4), 64, 0, stream>>>(sf + (size_t)rb * 8192, par, Uc);
      k3_gemm<<<dim3((r + 63) / 64, 4, 4), 256, 0, stream>>>(Uc, Wo, C2p, r);
      k4_ln<<<dim3((r + 3) / 4), 256, 0, stream>>>(
          C2p, bo, lnw, lnb, (float*)d_out + (size_t)rb * 256, r, 4);
    }
  }
}